// Round 13
// baseline (852.564 us; speedup 1.0000x reference)
//
#include <hip/hip_runtime.h>
#include <cstdint>

#define T_SEQ 2048
#define C_DIM 768
#define C3    2304
#define NH    12
#define HD    64
#define BT    8192            // B*T

typedef float f32x4 __attribute__((ext_vector_type(4)));
typedef short s16x8 __attribute__((ext_vector_type(8)));
typedef short s16x4 __attribute__((ext_vector_type(4)));

__device__ __forceinline__ unsigned short bf16_rtne(float x) {
    union { float f; unsigned u; } v; v.f = x;
    unsigned r = (v.u + 0x7FFFu + ((v.u >> 16) & 1u)) >> 16;
    return (unsigned short)r;
}
__device__ __forceinline__ float bf16_tof(unsigned short h) {
    union { float f; unsigned u; } v; v.u = ((unsigned)h) << 16;
    return v.f;
}

// ---------------------------------------------------------------------------
// Elementwise fp32 -> (hi, lo) bf16 split. Runs once per input array.
// ---------------------------------------------------------------------------
__global__ __launch_bounds__(256) void split_bf16(const float* __restrict__ in,
                                                  short* __restrict__ hi,
                                                  short* __restrict__ lo, int n4)
{
    for (int i = blockIdx.x * blockDim.x + threadIdx.x; i < n4; i += gridDim.x * blockDim.x) {
        const float4 v = *(const float4*)&in[(size_t)i * 4];
        unsigned short h0 = bf16_rtne(v.x), h1 = bf16_rtne(v.y),
                       h2 = bf16_rtne(v.z), h3 = bf16_rtne(v.w);
        *(s16x4*)&hi[(size_t)i * 4] = (s16x4){(short)h0, (short)h1, (short)h2, (short)h3};
        *(s16x4*)&lo[(size_t)i * 4] = (s16x4){(short)bf16_rtne(v.x - bf16_tof(h0)),
                                              (short)bf16_rtne(v.y - bf16_tof(h1)),
                                              (short)bf16_rtne(v.z - bf16_tof(h2)),
                                              (short)bf16_rtne(v.w - bf16_tof(h3))};
    }
}

// ---------------------------------------------------------------------------
// Split-bf16 MFMA GEMM on pre-split operands.
// C[M,N] = (Ah+Al)[M,K] @ (Bh+Bl)[N,K]^T + bias[N]  (3-term split)
// Tile 128x128, BK=32, 256 thr = 4 waves (2x2), wave tile 64x64 (4x4 frags).
// NEW this round:
//  (1) bijective XCD-chunked grid swizzle: 1D grid, xcd = bid&7; each XCD
//      gets 8 contiguous m-panels x all n (n fastest) -> A-panels (3.2 MB)
//      L2-resident per XCD, B from L3.  Grid % 8 == 0 (1152 / 384).
//  (2) register prefetch of next k-step staging loads, issued after the
//      post-store barrier so HBM/L2 latency hides under the MFMA phase.
// MODE 0: f32 C out.  MODE 1: QKV epilogue -> Qh/Ql (scaled), K bf16, V^T bf16.
// ---------------------------------------------------------------------------
template<int MODE, int MBLKS, int NBLKS>
__global__ __launch_bounds__(256, 4) void gemm_bt_bf16(
    const short* __restrict__ Ah_g, const short* __restrict__ Al_g,
    const short* __restrict__ Bh_g, const short* __restrict__ Bl_g,
    const float* __restrict__ bias, float* __restrict__ Cout,
    short* __restrict__ Qh, short* __restrict__ Ql,
    short* __restrict__ Kb, short* __restrict__ Vt,
    int M, int N, int K)
{
    __shared__ short Ah[128][40];
    __shared__ short Al[128][40];
    __shared__ short Bh[128][40];
    __shared__ short Bl[128][40];

    const int t    = threadIdx.x;
    const int w    = t >> 6;
    const int lane = t & 63;
    const int lr   = lane & 15;
    const int g    = lane >> 4;
    const int lk   = g * 8;

    // XCD-chunked bijective swizzle
    const int bid = blockIdx.x;
    const int xcd = bid & 7;
    const int cix = bid >> 3;
    const int m0  = (xcd * (MBLKS / 8) + cix / NBLKS) * 128;
    const int n0  = (cix % NBLKS) * 128;

    const int wm   = (w >> 1) * 64;
    const int wn   = (w & 1) * 64;

    // staging address components (fixed per thread); chunk i adds 64 rows
    const int srow  = t >> 2;           // 0..63
    const int scol8 = (t & 3) * 8;      // 0,8,16,24

    f32x4 acc[4][4];
#pragma unroll
    for (int i = 0; i < 4; ++i)
#pragma unroll
        for (int j = 0; j < 4; ++j) acc[i][j] = (f32x4){0.f, 0.f, 0.f, 0.f};

    // prologue: load k-step 0 into registers
    s16x8 pa[2], pal[2], pb[2], pbl[2];
#pragma unroll
    for (int i = 0; i < 2; ++i) {
        const int row   = srow + i * 64;
        const size_t ga = (size_t)(m0 + row) * K + scol8;
        const size_t gb = (size_t)(n0 + row) * K + scol8;
        pa[i]  = *(const s16x8*)&Ah_g[ga];
        pal[i] = *(const s16x8*)&Al_g[ga];
        pb[i]  = *(const s16x8*)&Bh_g[gb];
        pbl[i] = *(const s16x8*)&Bl_g[gb];
    }

    for (int kk = 0; kk < K; kk += 32) {
        // regs -> LDS
#pragma unroll
        for (int i = 0; i < 2; ++i) {
            const int row = srow + i * 64;
            *(s16x8*)&Ah[row][scol8] = pa[i];
            *(s16x8*)&Al[row][scol8] = pal[i];
            *(s16x8*)&Bh[row][scol8] = pb[i];
            *(s16x8*)&Bl[row][scol8] = pbl[i];
        }
        __syncthreads();

        // prefetch next k-step (in flight during the MFMA phase)
        if (kk + 32 < K) {
#pragma unroll
            for (int i = 0; i < 2; ++i) {
                const int row   = srow + i * 64;
                const size_t ga = (size_t)(m0 + row) * K + kk + 32 + scol8;
                const size_t gb = (size_t)(n0 + row) * K + kk + 32 + scol8;
                pa[i]  = *(const s16x8*)&Ah_g[ga];
                pal[i] = *(const s16x8*)&Al_g[ga];
                pb[i]  = *(const s16x8*)&Bh_g[gb];
                pbl[i] = *(const s16x8*)&Bl_g[gb];
            }
        }

        s16x8 afh[4], afl[4];
#pragma unroll
        for (int i = 0; i < 4; ++i) {
            afh[i] = *(const s16x8*)&Ah[wm + i * 16 + lr][lk];
            afl[i] = *(const s16x8*)&Al[wm + i * 16 + lr][lk];
        }
#pragma unroll
        for (int j = 0; j < 4; ++j) {
            const s16x8 bfh = *(const s16x8*)&Bh[wn + j * 16 + lr][lk];
            const s16x8 bfl = *(const s16x8*)&Bl[wn + j * 16 + lr][lk];
#pragma unroll
            for (int i = 0; i < 4; ++i) {
                acc[i][j] = __builtin_amdgcn_mfma_f32_16x16x32_bf16(afh[i], bfh, acc[i][j], 0, 0, 0);
                acc[i][j] = __builtin_amdgcn_mfma_f32_16x16x32_bf16(afh[i], bfl, acc[i][j], 0, 0, 0);
                acc[i][j] = __builtin_amdgcn_mfma_f32_16x16x32_bf16(afl[i], bfh, acc[i][j], 0, 0, 0);
            }
        }
        __syncthreads();
    }

    if (MODE == 0) {
#pragma unroll
        for (int j = 0; j < 4; ++j) {
            const float bj = bias[n0 + wn + j * 16 + lr];
#pragma unroll
            for (int i = 0; i < 4; ++i)
#pragma unroll
                for (int r = 0; r < 4; ++r) {
                    const int row = m0 + wm + i * 16 + g * 4 + r;
                    Cout[(size_t)row * N + n0 + wn + j * 16 + lr] = acc[i][j][r] + bj;
                }
        }
    } else {
        // QKV epilogue. Whole block is in one region (128-tiles don't straddle 768s).
        const int region = n0 / C_DIM;            // 0=Q, 1=K, 2=V
#pragma unroll
        for (int j = 0; j < 4; ++j) {
            const int n    = n0 + wn + j * 16 + lr;
            const float bj = bias[n];
            const int nr   = n - region * C_DIM;
            const int hh   = nr >> 6;             // head
            const int d    = nr & 63;
#pragma unroll
            for (int i = 0; i < 4; ++i) {
                const int rowb = m0 + wm + i * 16 + g * 4;
                const int b    = rowb >> 11;
                const int tt   = rowb & 2047;
                const size_t hb = (size_t)b * NH + hh;
                if (region == 0) {
#pragma unroll
                    for (int r = 0; r < 4; ++r) {
                        const float v = (acc[i][j][r] + bj) * 0.125f;
                        const unsigned short hv = bf16_rtne(v);
                        const size_t idx = (hb * T_SEQ + tt + r) * HD + d;
                        Qh[idx] = (short)hv;
                        Ql[idx] = (short)bf16_rtne(v - bf16_tof(hv));
                    }
                } else if (region == 1) {
#pragma unroll
                    for (int r = 0; r < 4; ++r) {
                        const float v = acc[i][j][r] + bj;
                        Kb[(hb * T_SEQ + tt + r) * HD + d] = (short)bf16_rtne(v);
                    }
                } else {
                    s16x4 pv;
#pragma unroll
                    for (int r = 0; r < 4; ++r) pv[r] = (short)bf16_rtne(acc[i][j][r] + bj);
                    *(s16x4*)&Vt[(hb * HD + d) * T_SEQ + tt] = pv;
                }
            }
        }
    }
}

// ---------------------------------------------------------------------------
// Flash attention (causal), 128-q blocks x 8 waves (512 threads).
// (unchanged from measured Round-12 version)
// ---------------------------------------------------------------------------
#define NEG_BIG (-3.402823466e+38f)

__global__ __launch_bounds__(512, 8) void flash_attn_bf16(
    const short* __restrict__ Qh, const short* __restrict__ Ql,
    const short* __restrict__ Kb, const short* __restrict__ Vt,
    short* __restrict__ yh, short* __restrict__ yl)
{
    __shared__ short Ks[64][72];
    __shared__ short Vs[64][72];
    __shared__ short Ps[128][72];
    __shared__ float redbuf[128];

    const int t = threadIdx.x;
    const int w = t >> 6;          // 0..7
    const int l = t & 63;
    const int c = l & 15;
    const int g = l >> 4;

    const int qt = gridDim.x - 1 - blockIdx.x;   // big tiles first
    const int bh = blockIdx.y;
    const int b  = bh / NH;
    const int hh = bh % NH;
    const int q0 = qt * 128;
    const int qwave = q0 + 16 * w;               // wave's lowest q row

    const size_t baseT = (size_t)bh * T_SEQ * HD;   // Q/K token-major base
    const size_t baseV = (size_t)bh * HD * T_SEQ;   // V^T base

    s16x8 qfh[2], qfl[2];
#pragma unroll
    for (int ds = 0; ds < 2; ++ds) {
        const size_t qi = baseT + (size_t)(qwave + c) * HD + ds * 32 + g * 8;
        qfh[ds] = *(const s16x8*)&Qh[qi];
        qfl[ds] = *(const s16x8*)&Ql[qi];
    }

    f32x4 o[4];
#pragma unroll
    for (int j = 0; j < 4; ++j) o[j] = (f32x4){0.f, 0.f, 0.f, 0.f};
    float m_run = NEG_BIG, l_run = 0.0f;

    const int nkt = (q0 + 128) / 64;             // k-tiles for this block
    for (int kt = 0; kt < nkt; ++kt) {
        const int k0 = kt * 64;
        // stage K [k][d] and V^T [d][k]: 512 threads, 1 chunk (16B) each
        {
            const int row  = t >> 3;             // 0..63
            const int col8 = (t & 7) * 8;        // 0..56
            *(s16x8*)&Ks[row][col8] = *(const s16x8*)&Kb[baseT + (size_t)(k0 + row) * HD + col8];
            *(s16x8*)&Vs[row][col8] = *(const s16x8*)&Vt[baseV + (size_t)row * T_SEQ + k0 + col8];
        }
        __syncthreads();

        if (k0 <= qwave + 15) {   // wave-uniform: skip all-masked tiles
            f32x4 s[4];
#pragma unroll
            for (int sm = 0; sm < 4; ++sm) {
                s[sm] = (f32x4){0.f, 0.f, 0.f, 0.f};
#pragma unroll
                for (int ds = 0; ds < 2; ++ds) {
                    const s16x8 kf = *(const s16x8*)&Ks[sm * 16 + c][ds * 32 + g * 8];
                    s[sm] = __builtin_amdgcn_mfma_f32_16x16x32_bf16(kf, qfh[ds], s[sm], 0, 0, 0);
                    s[sm] = __builtin_amdgcn_mfma_f32_16x16x32_bf16(kf, qfl[ds], s[sm], 0, 0, 0);
                }
            }

            if (k0 + 63 > qwave) {               // causal mask (wave-uniform guard)
                const int qg = qwave + c;
#pragma unroll
                for (int sm = 0; sm < 4; ++sm)
#pragma unroll
                    for (int r = 0; r < 4; ++r)
                        if (k0 + 16 * sm + 4 * g + r > qg) s[sm][r] = NEG_BIG;
            }

            float mt = NEG_BIG;
#pragma unroll
            for (int sm = 0; sm < 4; ++sm)
#pragma unroll
                for (int r = 0; r < 4; ++r) mt = fmaxf(mt, s[sm][r]);
            mt = fmaxf(mt, __shfl_xor(mt, 16));
            mt = fmaxf(mt, __shfl_xor(mt, 32));
            const float mn    = fmaxf(m_run, mt);
            const float alpha = __expf(m_run - mn);
            m_run = mn;

            float ls = 0.0f;
#pragma unroll
            for (int sm = 0; sm < 4; ++sm)
#pragma unroll
                for (int r = 0; r < 4; ++r) {
                    s[sm][r] = __expf(s[sm][r] - mn);
                    ls += s[sm][r];
                }
            ls += __shfl_xor(ls, 16);
            ls += __shfl_xor(ls, 32);
            l_run = l_run * alpha + ls;

            if (g == 0) redbuf[16 * w + c] = alpha;

#pragma unroll
            for (int sm = 0; sm < 4; ++sm)
                *(s16x4*)&Ps[16 * w + c][sm * 16 + g * 4] =
                    (s16x4){(short)bf16_rtne(s[sm][0]), (short)bf16_rtne(s[sm][1]),
                            (short)bf16_rtne(s[sm][2]), (short)bf16_rtne(s[sm][3])};

            {
                float av[4];
#pragma unroll
                for (int r = 0; r < 4; ++r) av[r] = redbuf[16 * w + 4 * g + r];
#pragma unroll
                for (int j = 0; j < 4; ++j)
#pragma unroll
                    for (int r = 0; r < 4; ++r) o[j][r] *= av[r];
            }

#pragma unroll
            for (int ks = 0; ks < 2; ++ks) {
                const s16x8 pf = *(const s16x8*)&Ps[16 * w + c][ks * 32 + g * 8];
#pragma unroll
                for (int j = 0; j < 4; ++j) {
                    const s16x8 vf = *(const s16x8*)&Vs[16 * j + c][ks * 32 + g * 8];
                    o[j] = __builtin_amdgcn_mfma_f32_16x16x32_bf16(pf, vf, o[j], 0, 0, 0);
                }
            }
        }
        __syncthreads();   // before next k-tile overwrites Ks/Vs
    }

    if (g == 0) redbuf[16 * w + c] = l_run;
    float linv[4];
#pragma unroll
    for (int r = 0; r < 4; ++r) linv[r] = 1.0f / redbuf[16 * w + 4 * g + r];
#pragma unroll
    for (int j = 0; j < 4; ++j)
#pragma unroll
        for (int r = 0; r < 4; ++r) {
            const float ov = o[j][r] * linv[r];
            const unsigned short hv = bf16_rtne(ov);
            const size_t idx = ((size_t)b * T_SEQ + qwave + 4 * g + r) * C_DIM
                               + hh * HD + 16 * j + c;
            yh[idx] = (short)hv;
            yl[idx] = (short)bf16_rtne(ov - bf16_tof(hv));
        }
}

// ---------------------------------------------------------------------------
extern "C" void kernel_launch(void* const* d_in, const int* in_sizes, int n_in,
                              void* d_out, int out_size, void* d_ws, size_t ws_size,
                              hipStream_t stream)
{
    (void)in_sizes; (void)n_in; (void)out_size; (void)ws_size;
    const float* x      = (const float*)d_in[0];
    const float* W_attn = (const float*)d_in[1];
    const float* b_attn = (const float*)d_in[2];
    const float* W_proj = (const float*)d_in[3];
    const float* b_proj = (const float*)d_in[4];
    float* out = (float*)d_out;

    const size_t SX  = (size_t)BT * C_DIM;      // 6291456
    const size_t SWA = (size_t)C3 * C_DIM;      // 1769472
    const size_t SWP = (size_t)C_DIM * C_DIM;   // 589824

    short* p   = (short*)d_ws;
    short* xh  = p;            p += SX;
    short* xl  = p;            p += SX;
    short* Wah = p;            p += SWA;
    short* Wal = p;            p += SWA;
    short* Wph = p;            p += SWP;
    short* Wpl = p;            p += SWP;
    short* Qh  = p;            p += SX;
    short* Ql  = p;            p += SX;
    short* Kb  = p;            p += SX;
    short* Vt  = p;            p += SX;
    short* yh  = xh;           // alias: x dead after gemm1
    short* yl  = xl;

    split_bf16<<<1024, 256, 0, stream>>>(x,      xh,  xl,  (int)(SX  / 4));
    split_bf16<<<512,  256, 0, stream>>>(W_attn, Wah, Wal, (int)(SWA / 4));
    split_bf16<<<256,  256, 0, stream>>>(W_proj, Wph, Wpl, (int)(SWP / 4));

    // qkv GEMM: grid 1152 = 8 XCD chunks x (8 m-panels x 18 n-panels)
    gemm_bt_bf16<1, 64, 18><<<dim3(64 * 18), 256, 0, stream>>>(
        xh, xl, Wah, Wal, b_attn, nullptr, Qh, Ql, Kb, Vt, BT, C3, C_DIM);

    flash_attn_bf16<<<dim3(T_SEQ / 128, 4 * NH), 512, 0, stream>>>(Qh, Ql, Kb, Vt, yh, yl);

    // proj GEMM: grid 384 = 8 XCD chunks x (8 m-panels x 6 n-panels)
    gemm_bt_bf16<0, 64, 6><<<dim3(64 * 6), 256, 0, stream>>>(
        yh, yl, Wph, Wpl, b_proj, out, nullptr, nullptr, nullptr, nullptr, BT, C_DIM, C_DIM);
}

// Round 14
// 395.057 us; speedup vs baseline: 2.1581x; 2.1581x over previous
//
#include <hip/hip_runtime.h>
#include <cstdint>

#define T_SEQ 2048
#define C_DIM 768
#define C3    2304
#define NH    12
#define HD    64
#define BT    8192            // B*T

typedef float f32x4 __attribute__((ext_vector_type(4)));
typedef short s16x8 __attribute__((ext_vector_type(8)));
typedef short s16x4 __attribute__((ext_vector_type(4)));

__device__ __forceinline__ unsigned short bf16_rtne(float x) {
    union { float f; unsigned u; } v; v.f = x;
    unsigned r = (v.u + 0x7FFFu + ((v.u >> 16) & 1u)) >> 16;
    return (unsigned short)r;
}
__device__ __forceinline__ float bf16_tof(unsigned short h) {
    union { float f; unsigned u; } v; v.u = ((unsigned)h) << 16;
    return v.f;
}

// ---------------------------------------------------------------------------
// Elementwise fp32 -> (hi, lo) bf16 split. Runs once per input array.
// ---------------------------------------------------------------------------
__global__ __launch_bounds__(256) void split_bf16(const float* __restrict__ in,
                                                  short* __restrict__ hi,
                                                  short* __restrict__ lo, int n4)
{
    for (int i = blockIdx.x * blockDim.x + threadIdx.x; i < n4; i += gridDim.x * blockDim.x) {
        const float4 v = *(const float4*)&in[(size_t)i * 4];
        unsigned short h0 = bf16_rtne(v.x), h1 = bf16_rtne(v.y),
                       h2 = bf16_rtne(v.z), h3 = bf16_rtne(v.w);
        *(s16x4*)&hi[(size_t)i * 4] = (s16x4){(short)h0, (short)h1, (short)h2, (short)h3};
        *(s16x4*)&lo[(size_t)i * 4] = (s16x4){(short)bf16_rtne(v.x - bf16_tof(h0)),
                                              (short)bf16_rtne(v.y - bf16_tof(h1)),
                                              (short)bf16_rtne(v.z - bf16_tof(h2)),
                                              (short)bf16_rtne(v.w - bf16_tof(h3))};
    }
}

// ---------------------------------------------------------------------------
// Split-bf16 MFMA GEMM on pre-split operands.
// C[M,N] = (Ah+Al)[M,K] @ (Bh+Bl)[N,K]^T + bias[N]  (3-term split)
// Tile 128x128, BK=32, 256 thr = 4 waves (2x2), wave tile 64x64 (4x4 frags).
// Staging: single-phase global->LDS (Round-12 form; NO cross-barrier register
// prefetch -- that spilled to scratch under the 128-VGPR cap and cost 3.3x).
// XCD-chunked bijective swizzle kept: xcd = bid&7 gets a contiguous m-chunk,
// n fastest, so per-XCD L2 keeps the A panels resident.
// MODE 0: f32 C out.  MODE 1: QKV epilogue -> Qh/Ql (scaled), K bf16, V^T bf16.
// ---------------------------------------------------------------------------
template<int MODE, int MBLKS, int NBLKS>
__global__ __launch_bounds__(256, 4) void gemm_bt_bf16(
    const short* __restrict__ Ah_g, const short* __restrict__ Al_g,
    const short* __restrict__ Bh_g, const short* __restrict__ Bl_g,
    const float* __restrict__ bias, float* __restrict__ Cout,
    short* __restrict__ Qh, short* __restrict__ Ql,
    short* __restrict__ Kb, short* __restrict__ Vt,
    int M, int N, int K)
{
    __shared__ short Ah[128][40];
    __shared__ short Al[128][40];
    __shared__ short Bh[128][40];
    __shared__ short Bl[128][40];

    const int t    = threadIdx.x;
    const int w    = t >> 6;
    const int lane = t & 63;
    const int lr   = lane & 15;
    const int g    = lane >> 4;
    const int lk   = g * 8;

    // XCD-chunked bijective swizzle
    const int bid = blockIdx.x;
    const int xcd = bid & 7;
    const int cix = bid >> 3;
    const int m0  = (xcd * (MBLKS / 8) + cix / NBLKS) * 128;
    const int n0  = (cix % NBLKS) * 128;

    const int wm   = (w >> 1) * 64;
    const int wn   = (w & 1) * 64;

    f32x4 acc[4][4];
#pragma unroll
    for (int i = 0; i < 4; ++i)
#pragma unroll
        for (int j = 0; j < 4; ++j) acc[i][j] = (f32x4){0.f, 0.f, 0.f, 0.f};

    for (int kk = 0; kk < K; kk += 32) {
#pragma unroll
        for (int i = 0; i < 2; ++i) {
            const int chunk = t + i * 256;        // 512 x 16B chunks per tile
            const int row   = chunk >> 2;         // 0..127
            const int col8  = (chunk & 3) * 8;    // 0,8,16,24
            const size_t ga = (size_t)(m0 + row) * K + kk + col8;
            const size_t gb = (size_t)(n0 + row) * K + kk + col8;
            *(s16x8*)&Ah[row][col8] = *(const s16x8*)&Ah_g[ga];
            *(s16x8*)&Al[row][col8] = *(const s16x8*)&Al_g[ga];
            *(s16x8*)&Bh[row][col8] = *(const s16x8*)&Bh_g[gb];
            *(s16x8*)&Bl[row][col8] = *(const s16x8*)&Bl_g[gb];
        }
        __syncthreads();

        s16x8 afh[4], afl[4];
#pragma unroll
        for (int i = 0; i < 4; ++i) {
            afh[i] = *(const s16x8*)&Ah[wm + i * 16 + lr][lk];
            afl[i] = *(const s16x8*)&Al[wm + i * 16 + lr][lk];
        }
#pragma unroll
        for (int j = 0; j < 4; ++j) {
            const s16x8 bfh = *(const s16x8*)&Bh[wn + j * 16 + lr][lk];
            const s16x8 bfl = *(const s16x8*)&Bl[wn + j * 16 + lr][lk];
#pragma unroll
            for (int i = 0; i < 4; ++i) {
                acc[i][j] = __builtin_amdgcn_mfma_f32_16x16x32_bf16(afh[i], bfh, acc[i][j], 0, 0, 0);
                acc[i][j] = __builtin_amdgcn_mfma_f32_16x16x32_bf16(afh[i], bfl, acc[i][j], 0, 0, 0);
                acc[i][j] = __builtin_amdgcn_mfma_f32_16x16x32_bf16(afl[i], bfh, acc[i][j], 0, 0, 0);
            }
        }
        __syncthreads();
    }

    if (MODE == 0) {
#pragma unroll
        for (int j = 0; j < 4; ++j) {
            const float bj = bias[n0 + wn + j * 16 + lr];
#pragma unroll
            for (int i = 0; i < 4; ++i)
#pragma unroll
                for (int r = 0; r < 4; ++r) {
                    const int row = m0 + wm + i * 16 + g * 4 + r;
                    Cout[(size_t)row * N + n0 + wn + j * 16 + lr] = acc[i][j][r] + bj;
                }
        }
    } else {
        // QKV epilogue. Whole block is in one region (128-tiles don't straddle 768s).
        const int region = n0 / C_DIM;            // 0=Q, 1=K, 2=V
#pragma unroll
        for (int j = 0; j < 4; ++j) {
            const int n    = n0 + wn + j * 16 + lr;
            const float bj = bias[n];
            const int nr   = n - region * C_DIM;
            const int hh   = nr >> 6;             // head
            const int d    = nr & 63;
#pragma unroll
            for (int i = 0; i < 4; ++i) {
                const int rowb = m0 + wm + i * 16 + g * 4;
                const int b    = rowb >> 11;
                const int tt   = rowb & 2047;
                const size_t hb = (size_t)b * NH + hh;
                if (region == 0) {
#pragma unroll
                    for (int r = 0; r < 4; ++r) {
                        const float v = (acc[i][j][r] + bj) * 0.125f;
                        const unsigned short hv = bf16_rtne(v);
                        const size_t idx = (hb * T_SEQ + tt + r) * HD + d;
                        Qh[idx] = (short)hv;
                        Ql[idx] = (short)bf16_rtne(v - bf16_tof(hv));
                    }
                } else if (region == 1) {
#pragma unroll
                    for (int r = 0; r < 4; ++r) {
                        const float v = acc[i][j][r] + bj;
                        Kb[(hb * T_SEQ + tt + r) * HD + d] = (short)bf16_rtne(v);
                    }
                } else {
                    s16x4 pv;
#pragma unroll
                    for (int r = 0; r < 4; ++r) pv[r] = (short)bf16_rtne(acc[i][j][r] + bj);
                    *(s16x4*)&Vt[(hb * HD + d) * T_SEQ + tt] = pv;
                }
            }
        }
    }
}

// ---------------------------------------------------------------------------
// Flash attention (causal), 128-q blocks x 8 waves (512 threads).
// (unchanged from measured Round-12 version)
// ---------------------------------------------------------------------------
#define NEG_BIG (-3.402823466e+38f)

__global__ __launch_bounds__(512, 8) void flash_attn_bf16(
    const short* __restrict__ Qh, const short* __restrict__ Ql,
    const short* __restrict__ Kb, const short* __restrict__ Vt,
    short* __restrict__ yh, short* __restrict__ yl)
{
    __shared__ short Ks[64][72];
    __shared__ short Vs[64][72];
    __shared__ short Ps[128][72];
    __shared__ float redbuf[128];

    const int t = threadIdx.x;
    const int w = t >> 6;          // 0..7
    const int l = t & 63;
    const int c = l & 15;
    const int g = l >> 4;

    const int qt = gridDim.x - 1 - blockIdx.x;   // big tiles first
    const int bh = blockIdx.y;
    const int b  = bh / NH;
    const int hh = bh % NH;
    const int q0 = qt * 128;
    const int qwave = q0 + 16 * w;               // wave's lowest q row

    const size_t baseT = (size_t)bh * T_SEQ * HD;   // Q/K token-major base
    const size_t baseV = (size_t)bh * HD * T_SEQ;   // V^T base

    s16x8 qfh[2], qfl[2];
#pragma unroll
    for (int ds = 0; ds < 2; ++ds) {
        const size_t qi = baseT + (size_t)(qwave + c) * HD + ds * 32 + g * 8;
        qfh[ds] = *(const s16x8*)&Qh[qi];
        qfl[ds] = *(const s16x8*)&Ql[qi];
    }

    f32x4 o[4];
#pragma unroll
    for (int j = 0; j < 4; ++j) o[j] = (f32x4){0.f, 0.f, 0.f, 0.f};
    float m_run = NEG_BIG, l_run = 0.0f;

    const int nkt = (q0 + 128) / 64;             // k-tiles for this block
    for (int kt = 0; kt < nkt; ++kt) {
        const int k0 = kt * 64;
        // stage K [k][d] and V^T [d][k]: 512 threads, 1 chunk (16B) each
        {
            const int row  = t >> 3;             // 0..63
            const int col8 = (t & 7) * 8;        // 0..56
            *(s16x8*)&Ks[row][col8] = *(const s16x8*)&Kb[baseT + (size_t)(k0 + row) * HD + col8];
            *(s16x8*)&Vs[row][col8] = *(const s16x8*)&Vt[baseV + (size_t)row * T_SEQ + k0 + col8];
        }
        __syncthreads();

        if (k0 <= qwave + 15) {   // wave-uniform: skip all-masked tiles
            f32x4 s[4];
#pragma unroll
            for (int sm = 0; sm < 4; ++sm) {
                s[sm] = (f32x4){0.f, 0.f, 0.f, 0.f};
#pragma unroll
                for (int ds = 0; ds < 2; ++ds) {
                    const s16x8 kf = *(const s16x8*)&Ks[sm * 16 + c][ds * 32 + g * 8];
                    s[sm] = __builtin_amdgcn_mfma_f32_16x16x32_bf16(kf, qfh[ds], s[sm], 0, 0, 0);
                    s[sm] = __builtin_amdgcn_mfma_f32_16x16x32_bf16(kf, qfl[ds], s[sm], 0, 0, 0);
                }
            }

            if (k0 + 63 > qwave) {               // causal mask (wave-uniform guard)
                const int qg = qwave + c;
#pragma unroll
                for (int sm = 0; sm < 4; ++sm)
#pragma unroll
                    for (int r = 0; r < 4; ++r)
                        if (k0 + 16 * sm + 4 * g + r > qg) s[sm][r] = NEG_BIG;
            }

            float mt = NEG_BIG;
#pragma unroll
            for (int sm = 0; sm < 4; ++sm)
#pragma unroll
                for (int r = 0; r < 4; ++r) mt = fmaxf(mt, s[sm][r]);
            mt = fmaxf(mt, __shfl_xor(mt, 16));
            mt = fmaxf(mt, __shfl_xor(mt, 32));
            const float mn    = fmaxf(m_run, mt);
            const float alpha = __expf(m_run - mn);
            m_run = mn;

            float ls = 0.0f;
#pragma unroll
            for (int sm = 0; sm < 4; ++sm)
#pragma unroll
                for (int r = 0; r < 4; ++r) {
                    s[sm][r] = __expf(s[sm][r] - mn);
                    ls += s[sm][r];
                }
            ls += __shfl_xor(ls, 16);
            ls += __shfl_xor(ls, 32);
            l_run = l_run * alpha + ls;

            if (g == 0) redbuf[16 * w + c] = alpha;

#pragma unroll
            for (int sm = 0; sm < 4; ++sm)
                *(s16x4*)&Ps[16 * w + c][sm * 16 + g * 4] =
                    (s16x4){(short)bf16_rtne(s[sm][0]), (short)bf16_rtne(s[sm][1]),
                            (short)bf16_rtne(s[sm][2]), (short)bf16_rtne(s[sm][3])};

            {
                float av[4];
#pragma unroll
                for (int r = 0; r < 4; ++r) av[r] = redbuf[16 * w + 4 * g + r];
#pragma unroll
                for (int j = 0; j < 4; ++j)
#pragma unroll
                    for (int r = 0; r < 4; ++r) o[j][r] *= av[r];
            }

#pragma unroll
            for (int ks = 0; ks < 2; ++ks) {
                const s16x8 pf = *(const s16x8*)&Ps[16 * w + c][ks * 32 + g * 8];
#pragma unroll
                for (int j = 0; j < 4; ++j) {
                    const s16x8 vf = *(const s16x8*)&Vs[16 * j + c][ks * 32 + g * 8];
                    o[j] = __builtin_amdgcn_mfma_f32_16x16x32_bf16(pf, vf, o[j], 0, 0, 0);
                }
            }
        }
        __syncthreads();   // before next k-tile overwrites Ks/Vs
    }

    if (g == 0) redbuf[16 * w + c] = l_run;
    float linv[4];
#pragma unroll
    for (int r = 0; r < 4; ++r) linv[r] = 1.0f / redbuf[16 * w + 4 * g + r];
#pragma unroll
    for (int j = 0; j < 4; ++j)
#pragma unroll
        for (int r = 0; r < 4; ++r) {
            const float ov = o[j][r] * linv[r];
            const unsigned short hv = bf16_rtne(ov);
            const size_t idx = ((size_t)b * T_SEQ + qwave + 4 * g + r) * C_DIM
                               + hh * HD + 16 * j + c;
            yh[idx] = (short)hv;
            yl[idx] = (short)bf16_rtne(ov - bf16_tof(hv));
        }
}

// ---------------------------------------------------------------------------
extern "C" void kernel_launch(void* const* d_in, const int* in_sizes, int n_in,
                              void* d_out, int out_size, void* d_ws, size_t ws_size,
                              hipStream_t stream)
{
    (void)in_sizes; (void)n_in; (void)out_size; (void)ws_size;
    const float* x      = (const float*)d_in[0];
    const float* W_attn = (const float*)d_in[1];
    const float* b_attn = (const float*)d_in[2];
    const float* W_proj = (const float*)d_in[3];
    const float* b_proj = (const float*)d_in[4];
    float* out = (float*)d_out;

    const size_t SX  = (size_t)BT * C_DIM;      // 6291456
    const size_t SWA = (size_t)C3 * C_DIM;      // 1769472
    const size_t SWP = (size_t)C_DIM * C_DIM;   // 589824

    short* p   = (short*)d_ws;
    short* xh  = p;            p += SX;
    short* xl  = p;            p += SX;
    short* Wah = p;            p += SWA;
    short* Wal = p;            p += SWA;
    short* Wph = p;            p += SWP;
    short* Wpl = p;            p += SWP;
    short* Qh  = p;            p += SX;
    short* Ql  = p;            p += SX;
    short* Kb  = p;            p += SX;
    short* Vt  = p;            p += SX;
    short* yh  = xh;           // alias: x dead after gemm1
    short* yl  = xl;

    split_bf16<<<1024, 256, 0, stream>>>(x,      xh,  xl,  (int)(SX  / 4));
    split_bf16<<<512,  256, 0, stream>>>(W_attn, Wah, Wal, (int)(SWA / 4));
    split_bf16<<<256,  256, 0, stream>>>(W_proj, Wph, Wpl, (int)(SWP / 4));

    // qkv GEMM: grid 1152 = 8 XCD chunks x (8 m-panels x 18 n-panels)
    gemm_bt_bf16<1, 64, 18><<<dim3(64 * 18), 256, 0, stream>>>(
        xh, xl, Wah, Wal, b_attn, nullptr, Qh, Ql, Kb, Vt, BT, C3, C_DIM);

    flash_attn_bf16<<<dim3(T_SEQ / 128, 4 * NH), 512, 0, stream>>>(Qh, Ql, Kb, Vt, yh, yl);

    // proj GEMM: grid 384 = 8 XCD chunks x (8 m-panels x 6 n-panels)
    gemm_bt_bf16<0, 64, 6><<<dim3(64 * 6), 256, 0, stream>>>(
        yh, yl, Wph, Wpl, b_proj, out, nullptr, nullptr, nullptr, nullptr, BT, C_DIM, C_DIM);
}